// Round 3
// baseline (97.448 us; speedup 1.0000x reference)
//
#include <hip/hip_runtime.h>

// Reference: Elman RNN scan over SEQ=2048, but output uses only out[0],
// i.e. the hidden state after the FIRST step with h0=0:
//   h1  = tanh(x[0] @ W_ih.T + b_ih + b_hh)   (BATCH, H)
//   out = relu(h1 @ W_fc.T + b_fc)            (BATCH, C)
// The 2048-step recurrence is dead code for the output.

#define RNN_SEQ   2048
#define RNN_BATCH 8192
#define RNN_IN    1
#define RNN_H     5
#define RNN_C     3

__global__ void Model_18021682774325_kernel(
    const float* __restrict__ x,      // (SEQ, BATCH, IN) — only first BATCH elems used
    const float* __restrict__ W_ih,   // (H, IN) = (5, 1)
    const float* __restrict__ b_ih,   // (H,)
    const float* __restrict__ b_hh,   // (H,)
    const float* __restrict__ W_fc,   // (C, H) = (3, 5)
    const float* __restrict__ b_fc,   // (C,)
    float* __restrict__ out)          // (BATCH, C)
{
    const int i = blockIdx.x * blockDim.x + threadIdx.x;
    if (i >= RNN_BATCH) return;

    // x[0, i, 0] — IN == 1, so the first-step input GEMM is a scalar multiply.
    const float xv = x[i];

    float h[RNN_H];
#pragma unroll
    for (int j = 0; j < RNN_H; ++j) {
        h[j] = tanhf(fmaf(xv, W_ih[j], b_ih[j] + b_hh[j]));
    }

#pragma unroll
    for (int c = 0; c < RNN_C; ++c) {
        float acc = b_fc[c];
#pragma unroll
        for (int j = 0; j < RNN_H; ++j) {
            acc = fmaf(h[j], W_fc[c * RNN_H + j], acc);
        }
        out[i * RNN_C + c] = fmaxf(acc, 0.0f);
    }
}

extern "C" void kernel_launch(void* const* d_in, const int* in_sizes, int n_in,
                              void* d_out, int out_size, void* d_ws, size_t ws_size,
                              hipStream_t stream) {
    // setup_inputs() order: x, W_ih, W_hh, b_ih, b_hh, W_fc, b_fc
    const float* x    = (const float*)d_in[0];
    const float* W_ih = (const float*)d_in[1];
    // d_in[2] = W_hh — unused (h0 == 0 for the only step that matters)
    const float* b_ih = (const float*)d_in[3];
    const float* b_hh = (const float*)d_in[4];
    const float* W_fc = (const float*)d_in[5];
    const float* b_fc = (const float*)d_in[6];
    float* out = (float*)d_out;

    const int threads = 256;
    const int blocks  = (RNN_BATCH + threads - 1) / threads;  // 32
    Model_18021682774325_kernel<<<blocks, threads, 0, stream>>>(
        x, W_ih, b_ih, b_hh, W_fc, b_fc, out);
}